// Round 1
// 118.316 us; speedup vs baseline: 1.0108x; 1.0108x over previous
//
#include <hip/hip_runtime.h>
#include <hip/hip_bf16.h>

typedef __bf16    bf16x8  __attribute__((ext_vector_type(8)));
typedef __bf16    bf16x4  __attribute__((ext_vector_type(4)));
typedef _Float16  half8   __attribute__((ext_vector_type(8)));
typedef _Float16  half4   __attribute__((ext_vector_type(4)));
typedef _Float16  half2   __attribute__((ext_vector_type(2)));
typedef float     floatx4 __attribute__((ext_vector_type(4)));

constexpr int Bc  = 2;
constexpr int Hc  = 16;
constexpr int Lc  = 2048;
constexpr int Dc  = 64;
constexpr int BHn = Bc * Hc;     // 32
constexpr int BM  = 128;         // query rows per block
constexpr int BN  = 128;         // keys per tile
constexpr int NQT = Lc / BM;     // 16 query tiles
constexpr int LDK = 72;          // Ks padded stride (bf16 elems)
constexpr int LDV = 136;         // VT padded stride (fp16 elems)
constexpr int SMEM_BYTES = 35840; // max(Ks+VT, Ored+zred)

static __device__ __forceinline__ half2 pack_f16(float a, float b) {
    return __builtin_bit_cast(half2, __builtin_amdgcn_cvt_pkrtz(a, b));
}

// ---- fused pre-pass: K fp32->bf16, V fp32 -> fp16 transposed+key-permuted ----
// V^T layout: [bh][d][pcol]; within each 32-key group key k5 -> column 8*((k5>>2)&3)+4*(k5>>4)+(k5&3)
__global__ void prep(const float* __restrict__ kp, const float* __restrict__ vp,
                     __bf16* __restrict__ k16, _Float16* __restrict__ v16) {
    const int bid = blockIdx.x, tid = threadIdx.x;
    if (bid < 1024) {
        const size_t base = (size_t)bid * 4096 + tid * 4;
        #pragma unroll
        for (int rep = 0; rep < 4; ++rep) {
            const size_t i = base + rep * 1024;
            floatx4 v = *(const floatx4*)(kp + i);
            bf16x4 b;
            b[0] = (__bf16)v[0]; b[1] = (__bf16)v[1]; b[2] = (__bf16)v[2]; b[3] = (__bf16)v[3];
            *(bf16x4*)(k16 + i) = b;
        }
    } else {
        const int vb  = bid - 1024;
        const int bh  = vb >> 5, kt = vb & 31;
        const int key = kt * 64 + (tid & 63);
        const int k5  = key & 31;
        const int pcol = (key & ~31) | (((k5 >> 2) & 3) * 8 + ((k5 >> 4) & 1) * 4 + (k5 & 3));
        const int d0  = (tid >> 6) * 16;
        const float* src = vp + ((size_t)bh * Lc + key) * Dc;
        _Float16*    dst = v16 + (size_t)bh * Dc * Lc + pcol;
        #pragma unroll
        for (int i = 0; i < 16; ++i) {
            const int d = d0 + i;
            dst[(size_t)d * Lc] = (_Float16)src[d];
        }
    }
}

// ---- main kernel: 512 blocks, complement-paired, 2x2 wave split (q-half x key-half) ----
// Each wave owns 64 q rows (wq) and 64 keys (wk): per-wave LDS reads halve vs all-key waves.
__global__ __launch_bounds__(256, 2)
void taylor_attn(const float* __restrict__ qp, const __bf16* __restrict__ k16,
                 const _Float16* __restrict__ v16, float* __restrict__ op)
{
    __shared__ __align__(16) char smem[SMEM_BYTES];
    __bf16*   Ks = (__bf16*)smem;               // [BN][LDK]  18432 B (also Q staging)
    _Float16* VT = (_Float16*)(smem + 18432);   // [Dc][LDV]  17408 B

    const int tid  = threadIdx.x;
    const int wv   = tid >> 6;
    const int lane = tid & 63;
    const int lm   = lane & 15;
    const int quad = lane >> 4;
    const int wq   = wv >> 1;   // q-half owner: rows [64*wq, 64*wq+64)
    const int wk   = wv & 1;    // key-half owner: keys [64*wk, 64*wk+64)

    const int cu    = (int)(blockIdx.x & 255);
    const int snd   = (int)(blockIdx.x >> 8);
    const int bh    = cu & 31;
    const int qslot = cu >> 5;
    const int qi    = snd ? qslot : (NQT - 1 - qslot);   // heavy tiles in the first 256
    const int q0    = qi * BM;
    const int jmax  = qi;

    const float*    qbase = qp  + ((size_t)bh * Lc + q0) * Dc;
    const __bf16*   kj    = k16 + (size_t)bh * Lc * Dc;   // pointer-bumped
    const _Float16* vj    = v16 + (size_t)bh * Dc * Lc;

    // ---- prefetch tile 0 into registers (in flight during Q staging) ----
    bf16x8 kr[4]; half8 vr[4];
    #pragma unroll
    for (int rep = 0; rep < 4; ++rep)
        kr[rep] = *(const bf16x8*)(kj + 8 * (tid + 256 * rep));
    #pragma unroll
    for (int rep = 0; rep < 4; ++rep) {
        const int g = tid + 256 * rep;                    // granule: row=d (g>>4), col=(g&15)*8
        vr[rep] = *(const half8*)(vj + (size_t)(g >> 4) * Lc + (g & 15) * 8);
    }

    // ---- stage Q (fp32 -> bf16) into Ks area, extract per-strip B-frags ----
    {
        const int r0 = tid >> 4, c4 = tid & 15;
        #pragma unroll
        for (int rep = 0; rep < 8; ++rep) {
            const int row = r0 + rep * 16;
            floatx4 v = *(const floatx4*)(qbase + row * Dc + c4 * 4);
            bf16x4 b;
            b[0] = (__bf16)v[0]; b[1] = (__bf16)v[1]; b[2] = (__bf16)v[2]; b[3] = (__bf16)v[3];
            *(bf16x4*)&Ks[row * LDK + c4 * 4] = b;
        }
    }
    __syncthreads();
    bf16x8 qa[4][2];   // [strip][kf]; B-frag: n=lm (qrow), k=kf*32+quad*8+j
    #pragma unroll
    for (int st = 0; st < 4; ++st)
        #pragma unroll
        for (int kf = 0; kf < 2; ++kf)
            qa[st][kf] = *(const bf16x8*)&Ks[(64 * wq + 16 * st + lm) * LDK + kf * 32 + quad * 8];
    __syncthreads();

    floatx4 oacc[4][4] = {};     // O^T partial (this wave's 64 keys): [strip][d-block]
    floatx4 zacc[4]    = {};     // z partial via ones-MFMA: every element = z[qrow=lm]

    const half8 ones = {(_Float16)1.f, (_Float16)1.f, (_Float16)1.f, (_Float16)1.f,
                        (_Float16)1.f, (_Float16)1.f, (_Float16)1.f, (_Float16)1.f};
    const half2 c8  = {(_Float16)0.125f, (_Float16)0.125f};
    const half2 c1  = {(_Float16)1.f,    (_Float16)1.f};
    const half2 ch  = {(_Float16)0.5f,   (_Float16)0.5f};

    for (int j = 0; j <= jmax; ++j) {
        // ---- write the prefetched tile into LDS (vmcnt waits only on these regs) ----
        #pragma unroll
        for (int rep = 0; rep < 4; ++rep) {
            const int c = tid + 256 * rep;
            *(bf16x8*)&Ks[(c >> 3) * LDK + (c & 7) * 8] = kr[rep];
        }
        #pragma unroll
        for (int rep = 0; rep < 4; ++rep) {
            const int g = tid + 256 * rep;
            *(half8*)&VT[(g >> 4) * LDV + (g & 15) * 8] = vr[rep];
        }
        __syncthreads();

        // ---- issue next tile's loads: a full compute phase to land ----
        if (j < jmax) {
            kj += BN * Dc;
            vj += BN;
            #pragma unroll
            for (int rep = 0; rep < 4; ++rep)
                kr[rep] = *(const bf16x8*)(kj + 8 * (tid + 256 * rep));
            #pragma unroll
            for (int rep = 0; rep < 4; ++rep) {
                const int g = tid + 256 * rep;
                vr[rep] = *(const half8*)(vj + (size_t)(g >> 4) * Lc + (g & 15) * 8);
            }
        }

        const bool nm = (j == jmax);                 // only the diagonal tile masks
        // ---- two 32-key sub-phases of this wave's 64 keys ----
        #pragma unroll
        for (int hf = 0; hf < 2; ++hf) {
            const int grp = 2 * wk + hf;             // 32-key group index within the 128-tile

            // S^T = K * Q^T for key rows [32*grp, 32*grp+32), all 4 q-strips
            floatx4 sacc[4][2] = {};
            #pragma unroll
            for (int kb4 = 0; kb4 < 2; ++kb4) {
                const int row0 = 16 * (4 * wk + 2 * hf + kb4);
                #pragma unroll
                for (int kf = 0; kf < 2; ++kf) {
                    bf16x8 ka = *(const bf16x8*)&Ks[(row0 + lm) * LDK + kf * 32 + quad * 8];
                    #pragma unroll
                    for (int st = 0; st < 4; ++st)
                        sacc[st][kb4] = __builtin_amdgcn_mfma_f32_16x16x32_bf16(ka, qa[st][kf], sacc[st][kb4], 0, 0, 0);
                }
            }

            // packed-f16 Taylor + causal mask; wf = W B-frags (registers only)
            half8 wf[4];
            #pragma unroll
            for (int st = 0; st < 4; ++st) {
                const int thr = q0 + 64 * wq + 16 * st + lm - j * BN;   // key threshold within tile
                half2 wh[2][2];
                #pragma unroll
                for (int kb4 = 0; kb4 < 2; ++kb4) {
                    half2 s01 = pack_f16(sacc[st][kb4][0], sacc[st][kb4][1]);
                    half2 s23 = pack_f16(sacc[st][kb4][2], sacc[st][kb4][3]);
                    half2 a01 = s01 * c8 + c1;            // fuses to v_pk_fma_f16
                    half2 a23 = s23 * c8 + c1;
                    half2 w01 = a01 * (a01 * ch) + ch;    // 0.5*a^2 + 0.5 = 1 + x + 0.5x^2
                    half2 w23 = a23 * (a23 * ch) + ch;
                    if (nm) {
                        const int i0 = 16 * (4 * wk + 2 * hf + kb4) + 4 * quad;
                        w01[0] = (i0 + 0 <= thr) ? w01[0] : (_Float16)0.f;
                        w01[1] = (i0 + 1 <= thr) ? w01[1] : (_Float16)0.f;
                        w23[0] = (i0 + 2 <= thr) ? w23[0] : (_Float16)0.f;
                        w23[1] = (i0 + 3 <= thr) ? w23[1] : (_Float16)0.f;
                    }
                    wh[kb4][0] = w01;
                    wh[kb4][1] = w23;
                }
                half4 lo = __builtin_shufflevector(wh[0][0], wh[0][1], 0, 1, 2, 3);
                half4 hi = __builtin_shufflevector(wh[1][0], wh[1][1], 0, 1, 2, 3);
                wf[st] = __builtin_shufflevector(lo, hi, 0, 1, 2, 3, 4, 5, 6, 7);
            }

            // O^T += V^T * W^T (K=32 f16) for this 32-key group; va reused across 4 strips
            #pragma unroll
            for (int db = 0; db < 4; ++db) {
                half8 va = *(const half8*)&VT[(16 * db + lm) * LDV + 32 * grp + 8 * quad];
                #pragma unroll
                for (int st = 0; st < 4; ++st)
                    oacc[st][db] = __builtin_amdgcn_mfma_f32_16x16x32_f16(va, wf[st], oacc[st][db], 0, 0, 0);
            }
            #pragma unroll
            for (int st = 0; st < 4; ++st)
                zacc[st] = __builtin_amdgcn_mfma_f32_16x16x32_f16(ones, wf[st], zacc[st], 0, 0, 0);
        }
        __syncthreads();   // all waves done reading Ks/VT before next iteration's write
    }

    // ---- epilogue: cross-wave (wk) reduction through LDS, normalize, store ----
    float* Ored = (float*)smem;             // [2][64][68] f32 = 34816 B (overlays Ks/VT)
    float* zred = (float*)(smem + 34816);   // [2][64]     f32 =   512 B
    if (wk) {
        #pragma unroll
        for (int st = 0; st < 4; ++st) {
            const int r = wq * 64 + 16 * st + lm;
            #pragma unroll
            for (int db = 0; db < 4; ++db)
                *(floatx4*)&Ored[(size_t)r * 68 + 16 * db + 4 * quad] = oacc[st][db];
            zred[r] = zacc[st][0];           // all quads write identical value (benign)
        }
    }
    __syncthreads();
    if (!wk) {
        #pragma unroll
        for (int st = 0; st < 4; ++st) {
            const int r = wq * 64 + 16 * st + lm;
            const float inv = 1.0f / (zacc[st][0] + zred[r] + 1e-6f);
            const int qrow = q0 + 64 * wq + 16 * st + lm;
            float* orow = op + ((size_t)bh * Lc + qrow) * Dc;
            #pragma unroll
            for (int db = 0; db < 4; ++db) {
                floatx4 part = *(const floatx4*)&Ored[(size_t)r * 68 + 16 * db + 4 * quad];
                floatx4 t = (oacc[st][db] + part) * inv;
                *(floatx4*)&orow[16 * db + 4 * quad] = t;
            }
        }
    }
}

extern "C" void kernel_launch(void* const* d_in, const int* in_sizes, int n_in,
                              void* d_out, int out_size, void* d_ws, size_t ws_size,
                              hipStream_t stream) {
    const float* q = (const float*)d_in[0];
    const float* k = (const float*)d_in[1];
    const float* v = (const float*)d_in[2];
    float* o = (float*)d_out;

    __bf16*   k16 = (__bf16*)d_ws;                                        // 8 MB
    _Float16* v16 = (_Float16*)((char*)d_ws + (size_t)BHn * Lc * Dc * 2); // 8 MB

    prep<<<dim3(2048), dim3(256), 0, stream>>>(k, v, k16, v16);
    taylor_attn<<<dim3(NQT * BHn), dim3(256), 0, stream>>>(q, k16, v16, o);
}

// Round 2
// 117.570 us; speedup vs baseline: 1.0172x; 1.0063x over previous
//
#include <hip/hip_runtime.h>
#include <hip/hip_bf16.h>

typedef __bf16    bf16x8  __attribute__((ext_vector_type(8)));
typedef __bf16    bf16x4  __attribute__((ext_vector_type(4)));
typedef _Float16  half8   __attribute__((ext_vector_type(8)));
typedef _Float16  half4   __attribute__((ext_vector_type(4)));
typedef _Float16  half2   __attribute__((ext_vector_type(2)));
typedef float     floatx4 __attribute__((ext_vector_type(4)));

constexpr int Bc  = 2;
constexpr int Hc  = 16;
constexpr int Lc  = 2048;
constexpr int Dc  = 64;
constexpr int BHn = Bc * Hc;     // 32
constexpr int BM  = 128;         // query rows per block
constexpr int BN  = 128;         // keys per tile
constexpr int NQT = Lc / BM;     // 16 query tiles
constexpr int LDK = 72;          // K padded stride (bf16 elems) -> row = 144 B
constexpr int LDV = 136;         // V^T padded stride (f16 elems) -> row = 272 B
constexpr int KBYTES = BN * LDK * 2;            // 18432
constexpr int VBYTES = Dc * LDV * 2;            // 17408
constexpr int TILE_BYTES = KBYTES + VBYTES;     // 35840 (= LDS image of one tile)
constexpr int TILE_GRANS = TILE_BYTES / 16;     // 2240 granules of 16 B

static __device__ __forceinline__ half2 pack_f16(float a, float b) {
    return __builtin_bit_cast(half2, __builtin_amdgcn_cvt_pkrtz(a, b));
}

static __device__ __forceinline__ void dma16(const void* g, void* l) {
    __builtin_amdgcn_global_load_lds(
        (const __attribute__((address_space(1))) void*)g,
        (__attribute__((address_space(3))) void*)l, 16, 0, 0);
}

// ---- pre-pass: write K/V tiles in the exact padded LDS image ----
// kv layout: [bh][tile=16][ K: 128 rows x 144 B | V^T: 64 rows x 272 B ] = 35840 B/tile
// V^T value at [d][pcol] = V[key(pcol)][d]; pcol permutation within each 32-key group:
// k5 -> 8*((k5>>2)&3) + 4*(k5>>4) + (k5&3)  (makes PV A-frags b128-contiguous)
__global__ void prep(const float* __restrict__ kp, const float* __restrict__ vp,
                     char* __restrict__ kv) {
    const int bid = blockIdx.x, tid = threadIdx.x;
    if (bid < 1024) {
        // K part: 1024 blocks x 256 threads; 4 threads per K row (16 d each)
        const int R    = bid * 64 + (tid >> 2);   // global row: bh*2048 + key
        const int s    = tid & 3;
        const int bh   = R >> 11;
        const int key  = R & 2047;
        const int tile = key >> 7;
        const int krow = key & 127;
        const float* src = kp + (size_t)R * 64 + s * 16;
        char* dst = kv + (size_t)(bh * 16 + tile) * TILE_BYTES + krow * 144 + s * 32;
        #pragma unroll
        for (int h = 0; h < 2; ++h) {
            floatx4 a = *(const floatx4*)(src + h * 8);
            floatx4 b = *(const floatx4*)(src + h * 8 + 4);
            bf16x8 o;
            o[0] = (__bf16)a[0]; o[1] = (__bf16)a[1]; o[2] = (__bf16)a[2]; o[3] = (__bf16)a[3];
            o[4] = (__bf16)b[0]; o[5] = (__bf16)b[1]; o[6] = (__bf16)b[2]; o[7] = (__bf16)b[3];
            *(bf16x8*)(dst + h * 16) = o;
        }
    } else {
        // V part: 1024 blocks; block handles 64 keys (half a tile) x 64 d
        const int vb   = bid - 1024;
        const int bh   = vb >> 5, kt = vb & 31;
        const int key  = kt * 64 + (tid & 63);
        const int tile = kt >> 1;
        const int kwt  = (kt & 1) * 64 + (tid & 63);   // key within tile
        const int k5   = kwt & 31;
        const int pcol = (kwt & ~31) | (((k5 >> 2) & 3) * 8 + ((k5 >> 4) & 1) * 4 + (k5 & 3));
        const int d0   = (tid >> 6) * 16;
        const float* src = vp + ((size_t)bh * Lc + key) * Dc;
        _Float16* dst = (_Float16*)(kv + (size_t)(bh * 16 + tile) * TILE_BYTES + KBYTES);
        #pragma unroll
        for (int i = 0; i < 16; ++i) {
            const int d = d0 + i;
            dst[(size_t)d * LDV + pcol] = (_Float16)src[d];
        }
    }
}

// ---- main kernel: double-buffered LDS, global_load_lds DMA, counted vmcnt ----
__global__ __launch_bounds__(256, 2)
void taylor_attn(const float* __restrict__ qp, const char* __restrict__ kv,
                 float* __restrict__ op)
{
    __shared__ __align__(16) char smem[2 * TILE_BYTES];   // 71680 B: buf0 | buf1

    const int tid  = threadIdx.x;
    const int wv   = tid >> 6;
    const int lane = tid & 63;
    const int lm   = lane & 15;
    const int quad = lane >> 4;
    const int wq   = wv >> 1;   // q-half owner: rows [64*wq, 64*wq+64)
    const int wk   = wv & 1;    // key-half owner: keys [64*wk, 64*wk+64)

    const int cu    = (int)(blockIdx.x & 255);
    const int snd   = (int)(blockIdx.x >> 8);
    const int bh    = cu & 31;
    const int qslot = cu >> 5;
    const int qi    = snd ? qslot : (NQT - 1 - qslot);   // complement-paired load balance
    const int q0    = qi * BM;
    const int jmax  = qi;

    const float* qbase = qp + ((size_t)bh * Lc + q0) * Dc;
    const char*  kvbh  = kv + (size_t)bh * 16 * TILE_BYTES;

    // ---- issue Q global loads first (oldest vmem), then tile-0 DMA into buf0 ----
    floatx4 qv[8];
    const int r0 = tid >> 4, c4 = tid & 15;
    #pragma unroll
    for (int rep = 0; rep < 8; ++rep)
        qv[rep] = *(const floatx4*)(qbase + (r0 + rep * 16) * Dc + c4 * 4);

    {
        const char* src = kvbh;          // tile 0
        char* dst = smem;                // buf0
        #pragma unroll
        for (int rep = 0; rep < 8; ++rep)
            dma16(src + (rep * 256 + tid) * 16, dst + (rep * 256 + tid) * 16);
        if (tid < 192)
            dma16(src + (2048 + tid) * 16, dst + (2048 + tid) * 16);
    }

    // ---- stage Q (fp32 -> bf16) into buf1's K area, extract per-strip B-frags ----
    {
        __bf16* Qs = (__bf16*)(smem + TILE_BYTES);
        #pragma unroll
        for (int rep = 0; rep < 8; ++rep) {
            bf16x4 b;
            b[0] = (__bf16)qv[rep][0]; b[1] = (__bf16)qv[rep][1];
            b[2] = (__bf16)qv[rep][2]; b[3] = (__bf16)qv[rep][3];
            *(bf16x4*)&Qs[(r0 + rep * 16) * LDK + c4 * 4] = b;
        }
    }
    asm volatile("s_waitcnt lgkmcnt(0)" ::: "memory");
    __builtin_amdgcn_s_barrier();

    bf16x8 qa[4][2];   // [strip][kf]; B-frag: n=lm (qrow), k=kf*32+quad*8+j
    {
        const __bf16* Qs = (const __bf16*)(smem + TILE_BYTES);
        #pragma unroll
        for (int st = 0; st < 4; ++st)
            #pragma unroll
            for (int kf = 0; kf < 2; ++kf)
                qa[st][kf] = *(const bf16x8*)&Qs[(64 * wq + 16 * st + lm) * LDK + kf * 32 + quad * 8];
    }
    asm volatile("s_waitcnt lgkmcnt(0)" ::: "memory");
    __builtin_amdgcn_s_barrier();

    floatx4 oacc[4][4] = {};     // O^T partial (this wave's 64 keys): [strip][d-block]
    floatx4 zacc[4]    = {};     // z partial via ones-MFMA

    const half8 ones = {(_Float16)1.f, (_Float16)1.f, (_Float16)1.f, (_Float16)1.f,
                        (_Float16)1.f, (_Float16)1.f, (_Float16)1.f, (_Float16)1.f};
    const half2 c8  = {(_Float16)0.125f, (_Float16)0.125f};
    const half2 c1  = {(_Float16)1.f,    (_Float16)1.f};
    const half2 ch  = {(_Float16)0.5f,   (_Float16)0.5f};

    for (int j = 0; j <= jmax; ++j) {
        const int cur = j & 1;
        const __bf16*   Kc = (const __bf16*)(smem + cur * TILE_BYTES);
        const _Float16* Vc = (const _Float16*)(smem + cur * TILE_BYTES + KBYTES);

        // ---- issue next tile's DMA into the other buffer; counted vmcnt (never 0) ----
        if (j < jmax) {
            const char* src = kvbh + (size_t)(j + 1) * TILE_BYTES;
            char* dst = smem + (cur ^ 1) * TILE_BYTES;
            #pragma unroll
            for (int rep = 0; rep < 8; ++rep)
                dma16(src + (rep * 256 + tid) * 16, dst + (rep * 256 + tid) * 16);
            if (tid < 192)
                dma16(src + (2048 + tid) * 16, dst + (2048 + tid) * 16);
            if (wv < 3) asm volatile("s_waitcnt vmcnt(9)" ::: "memory");
            else        asm volatile("s_waitcnt vmcnt(8)" ::: "memory");
        } else {
            asm volatile("s_waitcnt vmcnt(0)" ::: "memory");
        }
        __builtin_amdgcn_s_barrier();

        const bool nm = (j == jmax);                 // only the diagonal tile masks
        // ---- two 32-key sub-phases of this wave's 64 keys ----
        #pragma unroll
        for (int hf = 0; hf < 2; ++hf) {
            const int grp = 2 * wk + hf;             // 32-key group within the 128-tile

            // S^T = K * Q^T for key rows [32*grp, 32*grp+32), all 4 q-strips
            floatx4 sacc[4][2] = {};
            #pragma unroll
            for (int kb4 = 0; kb4 < 2; ++kb4) {
                const int row0 = 16 * (4 * wk + 2 * hf + kb4);
                #pragma unroll
                for (int kf = 0; kf < 2; ++kf) {
                    bf16x8 ka = *(const bf16x8*)&Kc[(row0 + lm) * LDK + kf * 32 + quad * 8];
                    #pragma unroll
                    for (int st = 0; st < 4; ++st)
                        sacc[st][kb4] = __builtin_amdgcn_mfma_f32_16x16x32_bf16(ka, qa[st][kf], sacc[st][kb4], 0, 0, 0);
                }
            }

            // packed-f16 Taylor + causal mask; wf = W B-frags (registers only)
            half8 wf[4];
            #pragma unroll
            for (int st = 0; st < 4; ++st) {
                const int thr = q0 + 64 * wq + 16 * st + lm - j * BN;
                half2 wh[2][2];
                #pragma unroll
                for (int kb4 = 0; kb4 < 2; ++kb4) {
                    half2 s01 = pack_f16(sacc[st][kb4][0], sacc[st][kb4][1]);
                    half2 s23 = pack_f16(sacc[st][kb4][2], sacc[st][kb4][3]);
                    half2 a01 = s01 * c8 + c1;            // fuses to v_pk_fma_f16
                    half2 a23 = s23 * c8 + c1;
                    half2 w01 = a01 * (a01 * ch) + ch;    // 0.5*a^2 + 0.5 = 1 + x + 0.5x^2
                    half2 w23 = a23 * (a23 * ch) + ch;
                    if (nm) {
                        const int i0 = 16 * (4 * wk + 2 * hf + kb4) + 4 * quad;
                        w01[0] = (i0 + 0 <= thr) ? w01[0] : (_Float16)0.f;
                        w01[1] = (i0 + 1 <= thr) ? w01[1] : (_Float16)0.f;
                        w23[0] = (i0 + 2 <= thr) ? w23[0] : (_Float16)0.f;
                        w23[1] = (i0 + 3 <= thr) ? w23[1] : (_Float16)0.f;
                    }
                    wh[kb4][0] = w01;
                    wh[kb4][1] = w23;
                }
                half4 lo = __builtin_shufflevector(wh[0][0], wh[0][1], 0, 1, 2, 3);
                half4 hi = __builtin_shufflevector(wh[1][0], wh[1][1], 0, 1, 2, 3);
                wf[st] = __builtin_shufflevector(lo, hi, 0, 1, 2, 3, 4, 5, 6, 7);
            }

            // O^T += V^T * W^T (K=32 f16) for this 32-key group; va reused across 4 strips
            #pragma unroll
            for (int db = 0; db < 4; ++db) {
                half8 va = *(const half8*)&Vc[(16 * db + lm) * LDV + 32 * grp + 8 * quad];
                #pragma unroll
                for (int st = 0; st < 4; ++st)
                    oacc[st][db] = __builtin_amdgcn_mfma_f32_16x16x32_f16(va, wf[st], oacc[st][db], 0, 0, 0);
            }
            #pragma unroll
            for (int st = 0; st < 4; ++st)
                zacc[st] = __builtin_amdgcn_mfma_f32_16x16x32_f16(ones, wf[st], zacc[st], 0, 0, 0);
        }

        asm volatile("s_waitcnt lgkmcnt(0)" ::: "memory");
        __builtin_amdgcn_s_barrier();   // readers done before next iter's DMA overwrites
    }

    // ---- epilogue: cross-wave (wk) reduction through LDS, normalize, store ----
    float* Ored = (float*)smem;                     // [128][68] f32 = 34816 B (in buf0)
    float* zred = (float*)(smem + 34816);           // [128]     f32 =   512 B
    if (wk) {
        #pragma unroll
        for (int st = 0; st < 4; ++st) {
            const int r = wq * 64 + 16 * st + lm;
            #pragma unroll
            for (int db = 0; db < 4; ++db)
                *(floatx4*)&Ored[(size_t)r * 68 + 16 * db + 4 * quad] = oacc[st][db];
            zred[r] = zacc[st][0];
        }
    }
    __syncthreads();
    if (!wk) {
        #pragma unroll
        for (int st = 0; st < 4; ++st) {
            const int r = wq * 64 + 16 * st + lm;
            const float inv = 1.0f / (zacc[st][0] + zred[r] + 1e-6f);
            const int qrow = q0 + 64 * wq + 16 * st + lm;
            float* orow = op + ((size_t)bh * Lc + qrow) * Dc;
            #pragma unroll
            for (int db = 0; db < 4; ++db) {
                floatx4 part = *(const floatx4*)&Ored[(size_t)r * 68 + 16 * db + 4 * quad];
                floatx4 t = (oacc[st][db] + part) * inv;
                *(floatx4*)&orow[16 * db + 4 * quad] = t;
            }
        }
    }
}

extern "C" void kernel_launch(void* const* d_in, const int* in_sizes, int n_in,
                              void* d_out, int out_size, void* d_ws, size_t ws_size,
                              hipStream_t stream) {
    const float* q = (const float*)d_in[0];
    const float* k = (const float*)d_in[1];
    const float* v = (const float*)d_in[2];
    float* o = (float*)d_out;

    char* kv = (char*)d_ws;   // 32 bh x 16 tiles x 35840 B = 18.35 MB

    prep<<<dim3(2048), dim3(256), 0, stream>>>(k, v, kv);
    taylor_attn<<<dim3(NQT * BHn), dim3(256), 0, stream>>>(q, kv, o);
}